// Round 3
// baseline (1243.083 us; speedup 1.0000x reference)
//
#include <hip/hip_runtime.h>
#include <hip/hip_fp16.h>

// SelfAttention (B=8, C=256, H=W=64): fp16-MFMA pipeline.
// Stages: convert W -> f16; transpose X -> Xt(HW,C); Q/K/V channel GEMMs
// (LDS-free, all operands contiguous 16B/lane); V,O view-transposes;
// flash attention (LDS-staged K/V, XOR-swizzled, P overlaid in K region,
// T14 async-STAGE split: next tile loaded to regs during softmax/PV);
// final Wp GEMM -> fp32 out.

using half8  = _Float16 __attribute__((ext_vector_type(8)));
using half4v = _Float16 __attribute__((ext_vector_type(4)));
using f32x4  = float    __attribute__((ext_vector_type(4)));

#define HWC 1048576  // 4096*256 elements per batch

// ---------------- W fp32 -> f16 ----------------
__global__ void k_convert_w(const float* __restrict__ wq, const float* __restrict__ wk,
                            const float* __restrict__ wv, const float* __restrict__ wp,
                            _Float16* __restrict__ out) {
  int idx = (blockIdx.x * 256 + threadIdx.x) * 4;  // over 4*65536
  const float* src = idx < 65536 ? wq : idx < 131072 ? wk : idx < 196608 ? wv : wp;
  float4 v = *reinterpret_cast<const float4*>(src + (idx & 65535));
  half4v h = { (_Float16)v.x, (_Float16)v.y, (_Float16)v.z, (_Float16)v.w };
  *reinterpret_cast<half4v*>(out + idx) = h;
}

// ---------------- transpose fp32 (R,S) -> f16 (S,R), 64x64 tiles ----------------
__global__ void k_transpose_f32(const float* __restrict__ in, _Float16* __restrict__ out,
                                int R, int S) {
  size_t base = (size_t)blockIdx.z * R * S;
  in += base; out += base;
  int r0 = blockIdx.y * 64, s0 = blockIdx.x * 64;
  __shared__ _Float16 tile[4096];
  char* tb = (char*)tile;
  int t = threadIdx.x;
#pragma unroll
  for (int i = 0; i < 4; ++i) {
    int row = i * 16 + (t >> 4);
    int co  = t & 15;
    float4 v = *reinterpret_cast<const float4*>(in + (size_t)(r0 + row) * S + s0 + co * 4);
    float vv[4] = {v.x, v.y, v.z, v.w};
#pragma unroll
    for (int e = 0; e < 4; ++e) {
      int sl = co * 4 + e;
      int byte = (sl * 128 + row * 2) ^ (((sl >> 3) & 7) << 4);
      *reinterpret_cast<_Float16*>(tb + byte) = (_Float16)vv[e];
    }
  }
  __syncthreads();
#pragma unroll
  for (int i = 0; i < 2; ++i) {
    int so  = i * 32 + (t >> 3);
    int co2 = t & 7;
    int byte = (so * 128 + co2 * 16) ^ (((so >> 3) & 7) << 4);
    uint4 v = *reinterpret_cast<const uint4*>(tb + byte);
    *reinterpret_cast<uint4*>(out + (size_t)(s0 + so) * R + r0 + co2 * 8) = v;
  }
}

// ---------------- transpose f16 (R,S) -> f16 (S,R), 64x64 tiles ----------------
__global__ void k_transpose_h16(const _Float16* __restrict__ in, _Float16* __restrict__ out,
                                int R, int S) {
  size_t base = (size_t)blockIdx.z * R * S;
  in += base; out += base;
  int r0 = blockIdx.y * 64, s0 = blockIdx.x * 64;
  __shared__ _Float16 tile[4096];
  char* tb = (char*)tile;
  int t = threadIdx.x;
#pragma unroll
  for (int i = 0; i < 2; ++i) {
    int row = i * 32 + (t >> 3);
    int co  = t & 7;
    half8 v = *reinterpret_cast<const half8*>(in + (size_t)(r0 + row) * S + s0 + co * 8);
#pragma unroll
    for (int e = 0; e < 8; ++e) {
      int sl = co * 8 + e;
      int byte = (sl * 128 + row * 2) ^ (((sl >> 3) & 7) << 4);
      *reinterpret_cast<_Float16*>(tb + byte) = v[e];
    }
  }
  __syncthreads();
#pragma unroll
  for (int i = 0; i < 2; ++i) {
    int so  = i * 32 + (t >> 3);
    int co2 = t & 7;
    int byte = (so * 128 + co2 * 16) ^ (((so >> 3) & 7) << 4);
    uint4 v = *reinterpret_cast<const uint4*>(tb + byte);
    *reinterpret_cast<uint4*>(out + (size_t)(s0 + so) * R + r0 + co2 * 8) = v;
  }
}

// ---------------- GEMM: Y[M,N] = A[M,K=256] * Bt[N,K=256]^T, batched ----------------
// All operands row-major; per-lane frag loads are contiguous 16B. No LDS.
template <bool OUT_F32>
__global__ __launch_bounds__(256) void k_gemm(const _Float16* __restrict__ A,
                                              const _Float16* __restrict__ Bt,
                                              void* __restrict__ Yv, int M, int N,
                                              long sA, long sB, long sY, float scale) {
  int b = blockIdx.z;
  A  += (size_t)b * sA;
  Bt += (size_t)b * sB;
  int n0 = blockIdx.x * 64, m0 = blockIdx.y * 64;
  int t = threadIdx.x, wave = t >> 6, lane = t & 63;
  int lm = lane & 15, lk8 = (lane >> 4) * 8;
  int nr = n0 + wave * 16 + lm;
  f32x4 zero = {0.f, 0.f, 0.f, 0.f};
  f32x4 acc[4] = {zero, zero, zero, zero};
#pragma unroll
  for (int ks = 0; ks < 8; ++ks) {
    half8 bf = *reinterpret_cast<const half8*>(Bt + (size_t)nr * 256 + ks * 32 + lk8);
#pragma unroll
    for (int mt = 0; mt < 4; ++mt) {
      half8 af = *reinterpret_cast<const half8*>(A + (size_t)(m0 + mt * 16 + lm) * 256 + ks * 32 + lk8);
      acc[mt] = __builtin_amdgcn_mfma_f32_16x16x32_f16(af, bf, acc[mt], 0, 0, 0);
    }
  }
  int rq = (lane >> 4) * 4;
#pragma unroll
  for (int mt = 0; mt < 4; ++mt) {
#pragma unroll
    for (int r = 0; r < 4; ++r) {
      size_t off = (size_t)(m0 + mt * 16 + rq + r) * N + n0 + wave * 16 + lm;
      float v = acc[mt][r] * scale;
      if (OUT_F32) reinterpret_cast<float*>(Yv)[(size_t)b * sY + off] = v;
      else reinterpret_cast<_Float16*>(Yv)[(size_t)b * sY + off] = (_Float16)v;
    }
  }
}

// ---------------- flash attention ----------------
// Q (HW,C) f16 (pre-scaled by 1/16), Kt (HW,C) f16, Vt (C,HW) f16; O (HW,C) f16.
// WG: 4 waves x 16 q-rows; KV blocks of 64 keys; K/V in XOR-swizzled LDS.
// LDS = 64 KB exactly: K [0,32K), V [32K,64K); P (2KB/wave) overlaid on K's
// first 8 KB after a barrier (K fully consumed by then).
// T14 async-STAGE: next K/V tile loaded into regs right after QK^T, written
// to LDS after the trailing barrier -> HBM/L2 latency hides under softmax+PV.
__global__ __launch_bounds__(256, 2) void k_attn(const _Float16* __restrict__ Q,
                                                 const _Float16* __restrict__ Kt,
                                                 const _Float16* __restrict__ Vt,
                                                 _Float16* __restrict__ O) {
  extern __shared__ char lds[];  // [0,32K): K (+P overlay)  [32K,64K): V
  int wg = blockIdx.x;
  int b = wg & 7, qt = wg >> 3;  // batch -> XCD pinning (blocks round-robin XCDs)
  const _Float16* Qb  = Q  + (size_t)b * HWC;
  const _Float16* Ktb = Kt + (size_t)b * HWC;
  const _Float16* Vtb = Vt + (size_t)b * HWC;
  _Float16* Ob = O + (size_t)b * HWC;
  int t = threadIdx.x, wave = t >> 6, lane = t & 63;
  int lm = lane & 15, lkb = lane >> 4;
  int q0 = qt * 64 + wave * 16;
  char* Plds = lds + wave * 2048;  // overlay on K region

  half8 qf[8];
#pragma unroll
  for (int ks = 0; ks < 8; ++ks)
    qf[ks] = *reinterpret_cast<const half8*>(Qb + (size_t)(q0 + lm) * 256 + ks * 32 + lkb * 8);

  f32x4 zero = {0.f, 0.f, 0.f, 0.f};
  f32x4 oacc[16];
#pragma unroll
  for (int i = 0; i < 16; ++i) oacc[i] = zero;
  float mrun[4] = {-1e30f, -1e30f, -1e30f, -1e30f};
  float lrun[4] = {0.f, 0.f, 0.f, 0.f};

  // staging registers (the cross-iteration double buffer)
  uint4 pk[8], pv[8];
#define LOADKV(kb_)                                                                   \
  {                                                                                   \
    const uint4* srcK = reinterpret_cast<const uint4*>(Ktb + (size_t)(kb_) * 64 * 256); \
    _Pragma("unroll") for (int i = 0; i < 8; ++i) pk[i] = srcK[i * 256 + t];          \
    _Pragma("unroll") for (int i = 0; i < 8; ++i) {                                   \
      int chunk = i * 256 + t;                                                        \
      int ch = chunk >> 3, co = chunk & 7;                                            \
      pv[i] = *reinterpret_cast<const uint4*>(Vtb + (size_t)ch * 4096 + (kb_) * 64 + co * 8); \
    }                                                                                 \
  }

  LOADKV(0);

#pragma unroll 1
  for (int kb = 0; kb < 64; ++kb) {
    // write staged regs -> LDS (vmcnt wait happens here, data mostly landed)
#pragma unroll
    for (int i = 0; i < 8; ++i) {
      int chunk = i * 256 + t;
      int row = chunk >> 5, co = chunk & 31;
      *reinterpret_cast<uint4*>(lds + ((row * 512 + co * 16) ^ ((row & 7) << 4))) = pk[i];
    }
#pragma unroll
    for (int i = 0; i < 8; ++i) {
      int chunk = i * 256 + t;
      int ch = chunk >> 3, co = chunk & 7;
      *reinterpret_cast<uint4*>(lds + 32768 + ((ch * 128 + co * 16) ^ ((ch & 7) << 4))) = pv[i];
    }
    __syncthreads();

    // S = Q Kt^T (already scaled by 1/sqrt(C) via Q)
    f32x4 sacc[4] = {zero, zero, zero, zero};
#pragma unroll
    for (int nt = 0; nt < 4; ++nt) {
      int krow = nt * 16 + lm;
#pragma unroll
      for (int ks = 0; ks < 8; ++ks) {
        half8 kf = *reinterpret_cast<const half8*>(
            lds + ((krow * 512 + ks * 64 + lkb * 16) ^ ((krow & 7) << 4)));
        sacc[nt] = __builtin_amdgcn_mfma_f32_16x16x32_f16(qf[ks], kf, sacc[nt], 0, 0, 0);
      }
    }

    // issue next tile's global loads now; latency hides under softmax+PV
    if (kb < 63) LOADKV(kb + 1);

    __syncthreads();  // all waves done reading K -> P overlay safe

    // online softmax (rows = lkb*4 + r; 16-lane col-groups reduce via shfl_xor)
    float p[4][4], mnew[4], alpha[4];
#pragma unroll
    for (int r = 0; r < 4; ++r) {
      float mx = fmaxf(fmaxf(sacc[0][r], sacc[1][r]), fmaxf(sacc[2][r], sacc[3][r]));
#pragma unroll
      for (int m = 1; m < 16; m <<= 1) mx = fmaxf(mx, __shfl_xor(mx, m, 64));
      mnew[r] = fmaxf(mrun[r], mx);
      alpha[r] = exp2f((mrun[r] - mnew[r]) * 1.4426950408889634f);
      mrun[r] = mnew[r];
    }
#pragma unroll
    for (int r = 0; r < 4; ++r) {
      float s = 0.f;
#pragma unroll
      for (int nt = 0; nt < 4; ++nt) {
        p[nt][r] = exp2f((sacc[nt][r] - mnew[r]) * 1.4426950408889634f);
        s += p[nt][r];
      }
#pragma unroll
      for (int m = 1; m < 16; m <<= 1) s += __shfl_xor(s, m, 64);
      lrun[r] = lrun[r] * alpha[r] + s;
    }
#pragma unroll
    for (int ct = 0; ct < 16; ++ct)
#pragma unroll
      for (int r = 0; r < 4; ++r) oacc[ct][r] *= alpha[r];

    // P -> per-wave LDS slice (swizzled) for A-frag reads (own-wave only)
#pragma unroll
    for (int nt = 0; nt < 4; ++nt) {
#pragma unroll
      for (int r = 0; r < 4; ++r) {
        int prow = lkb * 4 + r, key = nt * 16 + lm;
        *reinterpret_cast<_Float16*>(Plds + ((prow * 128 + key * 2) ^ ((prow & 7) << 4))) =
            (_Float16)p[nt][r];
      }
    }

    // O += P @ V
#pragma unroll
    for (int ks2 = 0; ks2 < 2; ++ks2) {
      half8 pf = *reinterpret_cast<const half8*>(
          Plds + ((lm * 128 + ks2 * 64 + lkb * 16) ^ ((lm & 7) << 4)));
#pragma unroll
      for (int ct = 0; ct < 16; ++ct) {
        int vrow = ct * 16 + lm;
        half8 vf = *reinterpret_cast<const half8*>(
            lds + 32768 + ((vrow * 128 + ks2 * 64 + lkb * 16) ^ ((vrow & 7) << 4)));
        oacc[ct] = __builtin_amdgcn_mfma_f32_16x16x32_f16(pf, vf, oacc[ct], 0, 0, 0);
      }
    }
    __syncthreads();  // all P/V reads done before next stage overwrites
  }
#undef LOADKV

  float inv[4];
#pragma unroll
  for (int r = 0; r < 4; ++r) inv[r] = 1.0f / lrun[r];
#pragma unroll
  for (int ct = 0; ct < 16; ++ct) {
#pragma unroll
    for (int r = 0; r < 4; ++r) {
      Ob[(size_t)(q0 + lkb * 4 + r) * 256 + ct * 16 + lm] = (_Float16)(oacc[ct][r] * inv[r]);
    }
  }
}

// ---------------- launcher ----------------
// Workspace layout (MB offsets), 65 MB peak:
//   Wbf  @0    (0.5MB)
//   Xt   @1..17   -> reused as Vtb after V gemm
//   Qb   @17..33  -> reused as L (O-transpose) after attn
//   Ktb  @33..49
//   Vc   @49..65  -> reused as Ob after V-transpose
extern "C" void kernel_launch(void* const* d_in, const int* in_sizes, int n_in,
                              void* d_out, int out_size, void* d_ws, size_t ws_size,
                              hipStream_t stream) {
  (void)in_sizes; (void)n_in; (void)out_size; (void)ws_size;
  const float* X  = (const float*)d_in[0];
  const float* Wq = (const float*)d_in[1];
  const float* Wk = (const float*)d_in[2];
  const float* Wv = (const float*)d_in[3];
  const float* Wp = (const float*)d_in[4];

  char* ws = (char*)d_ws;
  _Float16* Wbf = (_Float16*)ws;                    // 4 x 65536 f16
  _Float16* Xt  = (_Float16*)(ws + (1ull  << 20));  // (B,HW,C) f16
  _Float16* Qb  = (_Float16*)(ws + (17ull << 20));  // flat (C,HW) == view (HW,C)
  _Float16* Ktb = (_Float16*)(ws + (33ull << 20));  // (HW,C) = Kc^T
  _Float16* Vc  = (_Float16*)(ws + (49ull << 20));  // temp V flat (C,HW)
  _Float16* Vtb = Xt;                               // (C,HW) view-transpose of V
  _Float16* Ob  = Vc;                               // attn out flat (HW,C)
  _Float16* Lb  = Qb;                               // O-chw-view transposed (HW,C)

  // W -> f16
  k_convert_w<<<256, 256, 0, stream>>>(Wq, Wk, Wv, Wp, Wbf);
  // X (B,256,4096) fp32 -> Xt (B,4096,256) f16
  k_transpose_f32<<<dim3(64, 4, 8), 256, 0, stream>>>(X, Xt, 256, 4096);
  // Q = Wq @ X, scaled 1/sqrt(256), flat (256,4096) f16
  k_gemm<false><<<dim3(64, 4, 8), 256, 0, stream>>>(Wbf, Xt, Qb, 256, 4096, 0, HWC, HWC, 0.0625f);
  // Kt[l][c] = (Wk @ X)^T, produced directly via role swap
  k_gemm<false><<<dim3(4, 64, 8), 256, 0, stream>>>(Xt, Wbf + 65536, Ktb, 4096, 256, HWC, 0, HWC, 1.0f);
  // Vc = Wv @ X flat (256,4096)
  k_gemm<false><<<dim3(64, 4, 8), 256, 0, stream>>>(Wbf + 131072, Xt, Vc, 256, 4096, 0, HWC, HWC, 1.0f);
  // Vt = transpose of V-view (4096,256) -> (256,4096)   [writes over Xt: dead]
  k_transpose_h16<<<dim3(4, 64, 8), 256, 0, stream>>>(Vc, Vtb, 4096, 256);
  // flash attention -> O flat (4096,256)                [writes over Vc: dead]
  k_attn<<<512, 256, 65536, stream>>>(Qb, Ktb, Vtb, Ob);
  // L = transpose of O-chw-view (256,4096) -> (4096,256) [writes over Qb: dead]
  k_transpose_h16<<<dim3(64, 4, 8), 256, 0, stream>>>(Ob, Lb, 256, 4096);
  // out = Wp @ O_chw, fp32
  k_gemm<true><<<dim3(64, 4, 8), 256, 0, stream>>>(Wbf + 196608, Lb, d_out, 256, 4096, 0, HWC, HWC, 1.0f);
}

// Round 4
// 547.225 us; speedup vs baseline: 2.2716x; 2.2716x over previous
//
#include <hip/hip_runtime.h>
#include <hip/hip_fp16.h>

// SelfAttention (B=8, C=256, H=W=64): fp16-MFMA pipeline.
// Stages: convert W -> f16; transpose X -> Xt(HW,C); Q/K/V channel GEMMs
// (LDS-free, all operands contiguous 16B/lane); V,O view-transposes;
// flash attention (async global_load_lds staging with PRE-SWIZZLED source,
// XOR-swizzled LDS reads, P overlaid in K region); final Wp GEMM -> fp32 out.
//
// R3 note: reg-prefetch (T14) removed — it spilled (VGPR_Count=128, 2.07 GB
// scratch writes/dispatch, kernel became scratch-BW-bound at 1017us).
// global_load_lds has zero VGPR cost; swizzle moved to the global source
// address (rule #21: LDS dest must be linear).

using half8  = _Float16 __attribute__((ext_vector_type(8)));
using half4v = _Float16 __attribute__((ext_vector_type(4)));
using f32x4  = float    __attribute__((ext_vector_type(4)));

#define HWC 1048576  // 4096*256 elements per batch

#define G2L(gp, lp)                                                   \
  __builtin_amdgcn_global_load_lds(                                   \
      (const __attribute__((address_space(1))) void*)(gp),            \
      (__attribute__((address_space(3))) void*)(lp), 16, 0, 0)

// ---------------- W fp32 -> f16 ----------------
__global__ void k_convert_w(const float* __restrict__ wq, const float* __restrict__ wk,
                            const float* __restrict__ wv, const float* __restrict__ wp,
                            _Float16* __restrict__ out) {
  int idx = (blockIdx.x * 256 + threadIdx.x) * 4;  // over 4*65536
  const float* src = idx < 65536 ? wq : idx < 131072 ? wk : idx < 196608 ? wv : wp;
  float4 v = *reinterpret_cast<const float4*>(src + (idx & 65535));
  half4v h = { (_Float16)v.x, (_Float16)v.y, (_Float16)v.z, (_Float16)v.w };
  *reinterpret_cast<half4v*>(out + idx) = h;
}

// ---------------- transpose fp32 (R,S) -> f16 (S,R), 64x64 tiles ----------------
__global__ void k_transpose_f32(const float* __restrict__ in, _Float16* __restrict__ out,
                                int R, int S) {
  size_t base = (size_t)blockIdx.z * R * S;
  in += base; out += base;
  int r0 = blockIdx.y * 64, s0 = blockIdx.x * 64;
  __shared__ _Float16 tile[4096];
  char* tb = (char*)tile;
  int t = threadIdx.x;
#pragma unroll
  for (int i = 0; i < 4; ++i) {
    int row = i * 16 + (t >> 4);
    int co  = t & 15;
    float4 v = *reinterpret_cast<const float4*>(in + (size_t)(r0 + row) * S + s0 + co * 4);
    float vv[4] = {v.x, v.y, v.z, v.w};
#pragma unroll
    for (int e = 0; e < 4; ++e) {
      int sl = co * 4 + e;
      int byte = (sl * 128 + row * 2) ^ (((sl >> 3) & 7) << 4);
      *reinterpret_cast<_Float16*>(tb + byte) = (_Float16)vv[e];
    }
  }
  __syncthreads();
#pragma unroll
  for (int i = 0; i < 2; ++i) {
    int so  = i * 32 + (t >> 3);
    int co2 = t & 7;
    int byte = (so * 128 + co2 * 16) ^ (((so >> 3) & 7) << 4);
    uint4 v = *reinterpret_cast<const uint4*>(tb + byte);
    *reinterpret_cast<uint4*>(out + (size_t)(s0 + so) * R + r0 + co2 * 8) = v;
  }
}

// ---------------- transpose f16 (R,S) -> f16 (S,R), 64x64 tiles ----------------
__global__ void k_transpose_h16(const _Float16* __restrict__ in, _Float16* __restrict__ out,
                                int R, int S) {
  size_t base = (size_t)blockIdx.z * R * S;
  in += base; out += base;
  int r0 = blockIdx.y * 64, s0 = blockIdx.x * 64;
  __shared__ _Float16 tile[4096];
  char* tb = (char*)tile;
  int t = threadIdx.x;
#pragma unroll
  for (int i = 0; i < 2; ++i) {
    int row = i * 32 + (t >> 3);
    int co  = t & 7;
    half8 v = *reinterpret_cast<const half8*>(in + (size_t)(r0 + row) * S + s0 + co * 8);
#pragma unroll
    for (int e = 0; e < 8; ++e) {
      int sl = co * 8 + e;
      int byte = (sl * 128 + row * 2) ^ (((sl >> 3) & 7) << 4);
      *reinterpret_cast<_Float16*>(tb + byte) = v[e];
    }
  }
  __syncthreads();
#pragma unroll
  for (int i = 0; i < 2; ++i) {
    int so  = i * 32 + (t >> 3);
    int co2 = t & 7;
    int byte = (so * 128 + co2 * 16) ^ (((so >> 3) & 7) << 4);
    uint4 v = *reinterpret_cast<const uint4*>(tb + byte);
    *reinterpret_cast<uint4*>(out + (size_t)(s0 + so) * R + r0 + co2 * 8) = v;
  }
}

// ---------------- GEMM: Y[M,N] = A[M,K=256] * Bt[N,K=256]^T, batched ----------------
// All operands row-major; per-lane frag loads are contiguous 16B. No LDS.
template <bool OUT_F32>
__global__ __launch_bounds__(256) void k_gemm(const _Float16* __restrict__ A,
                                              const _Float16* __restrict__ Bt,
                                              void* __restrict__ Yv, int M, int N,
                                              long sA, long sB, long sY, float scale) {
  int b = blockIdx.z;
  A  += (size_t)b * sA;
  Bt += (size_t)b * sB;
  int n0 = blockIdx.x * 64, m0 = blockIdx.y * 64;
  int t = threadIdx.x, wave = t >> 6, lane = t & 63;
  int lm = lane & 15, lk8 = (lane >> 4) * 8;
  int nr = n0 + wave * 16 + lm;
  f32x4 zero = {0.f, 0.f, 0.f, 0.f};
  f32x4 acc[4] = {zero, zero, zero, zero};
#pragma unroll
  for (int ks = 0; ks < 8; ++ks) {
    half8 bf = *reinterpret_cast<const half8*>(Bt + (size_t)nr * 256 + ks * 32 + lk8);
#pragma unroll
    for (int mt = 0; mt < 4; ++mt) {
      half8 af = *reinterpret_cast<const half8*>(A + (size_t)(m0 + mt * 16 + lm) * 256 + ks * 32 + lk8);
      acc[mt] = __builtin_amdgcn_mfma_f32_16x16x32_f16(af, bf, acc[mt], 0, 0, 0);
    }
  }
  int rq = (lane >> 4) * 4;
#pragma unroll
  for (int mt = 0; mt < 4; ++mt) {
#pragma unroll
    for (int r = 0; r < 4; ++r) {
      size_t off = (size_t)(m0 + mt * 16 + rq + r) * N + n0 + wave * 16 + lm;
      float v = acc[mt][r] * scale;
      if (OUT_F32) reinterpret_cast<float*>(Yv)[(size_t)b * sY + off] = v;
      else reinterpret_cast<_Float16*>(Yv)[(size_t)b * sY + off] = (_Float16)v;
    }
  }
}

// ---------------- flash attention ----------------
// Q (HW,C) f16 (pre-scaled by 1/16), Kt (HW,C) f16, Vt (C,HW) f16; O (HW,C) f16.
// WG: 4 waves x 16 q-rows; KV blocks of 64 keys.
// LDS = 64 KB exactly: K [0,32K), V [32K,64K); P (2KB/wave) overlaid on K's
// first 8 KB after a barrier (K fully consumed by then).
// Staging: global_load_lds width=16, LINEAR LDS dest, source chunk index
// pre-swizzled with the same involution the readers apply (rule #21).
__global__ __launch_bounds__(256, 2) void k_attn(const _Float16* __restrict__ Q,
                                                 const _Float16* __restrict__ Kt,
                                                 const _Float16* __restrict__ Vt,
                                                 _Float16* __restrict__ O) {
  extern __shared__ char lds[];  // [0,32K): K (+P overlay)  [32K,64K): V
  int wg = blockIdx.x;
  int b = wg & 7, qt = wg >> 3;  // batch -> XCD pinning (blocks round-robin XCDs)
  const _Float16* Qb  = Q  + (size_t)b * HWC;
  const _Float16* Ktb = Kt + (size_t)b * HWC;
  const _Float16* Vtb = Vt + (size_t)b * HWC;
  _Float16* Ob = O + (size_t)b * HWC;
  int t = threadIdx.x, wave = t >> 6, lane = t & 63;
  int lm = lane & 15, lkb = lane >> 4;
  int q0 = qt * 64 + wave * 16;
  char* Plds = lds + wave * 2048;  // overlay on K region

  half8 qf[8];
#pragma unroll
  for (int ks = 0; ks < 8; ++ks)
    qf[ks] = *reinterpret_cast<const half8*>(Qb + (size_t)(q0 + lm) * 256 + ks * 32 + lkb * 8);

  f32x4 zero = {0.f, 0.f, 0.f, 0.f};
  f32x4 oacc[16];
#pragma unroll
  for (int i = 0; i < 16; ++i) oacc[i] = zero;
  float mrun[4] = {-1e30f, -1e30f, -1e30f, -1e30f};
  float lrun[4] = {0.f, 0.f, 0.f, 0.f};

#pragma unroll 1
  for (int kb = 0; kb < 64; ++kb) {
    // --- async stage K tile (64 keys x 256 ch = 2048 x 16B chunks) ---
    // dest chunk c = i*256 + t is linear in LDS; source chunk = c ^ (row&7)
    // (row = c>>5) so the linear write lands in the swizzled layout.
#pragma unroll
    for (int i = 0; i < 8; ++i) {
      int c = i * 256 + t;
      int sk = (c ^ ((c >> 5) & 7)) * 8;  // element offset within K tile
      G2L(Ktb + (size_t)kb * 16384 + sk, lds + i * 4096 + wave * 1024);
    }
    // --- async stage V tile (256 ch x 64 keys) from Vt (C,HW) ---
    // dest chunk c: ch = c>>3, co = c&7; source co pre-swizzled by ch&7.
#pragma unroll
    for (int i = 0; i < 8; ++i) {
      int c = i * 256 + t;
      int ch = c >> 3, cov = (c & 7) ^ (ch & 7);
      G2L(Vtb + (size_t)ch * 4096 + kb * 64 + cov * 8, lds + 32768 + i * 4096 + wave * 1024);
    }
    __syncthreads();  // compiler drains vmcnt(0) before s_barrier -> data landed

    // S = Q Kt^T (already scaled by 1/sqrt(C) via Q)
    f32x4 sacc[4] = {zero, zero, zero, zero};
#pragma unroll
    for (int nt = 0; nt < 4; ++nt) {
      int krow = nt * 16 + lm;
#pragma unroll
      for (int ks = 0; ks < 8; ++ks) {
        half8 kf = *reinterpret_cast<const half8*>(
            lds + ((krow * 512 + ks * 64 + lkb * 16) ^ ((krow & 7) << 4)));
        sacc[nt] = __builtin_amdgcn_mfma_f32_16x16x32_f16(qf[ks], kf, sacc[nt], 0, 0, 0);
      }
    }
    __syncthreads();  // all waves done reading K -> P overlay safe

    // online softmax (rows = lkb*4 + r; 16-lane col-groups reduce via shfl_xor)
    float p[4][4], mnew[4], alpha[4];
#pragma unroll
    for (int r = 0; r < 4; ++r) {
      float mx = fmaxf(fmaxf(sacc[0][r], sacc[1][r]), fmaxf(sacc[2][r], sacc[3][r]));
#pragma unroll
      for (int m = 1; m < 16; m <<= 1) mx = fmaxf(mx, __shfl_xor(mx, m, 64));
      mnew[r] = fmaxf(mrun[r], mx);
      alpha[r] = exp2f((mrun[r] - mnew[r]) * 1.4426950408889634f);
      mrun[r] = mnew[r];
    }
#pragma unroll
    for (int r = 0; r < 4; ++r) {
      float s = 0.f;
#pragma unroll
      for (int nt = 0; nt < 4; ++nt) {
        p[nt][r] = exp2f((sacc[nt][r] - mnew[r]) * 1.4426950408889634f);
        s += p[nt][r];
      }
#pragma unroll
      for (int m = 1; m < 16; m <<= 1) s += __shfl_xor(s, m, 64);
      lrun[r] = lrun[r] * alpha[r] + s;
    }
#pragma unroll
    for (int ct = 0; ct < 16; ++ct)
#pragma unroll
      for (int r = 0; r < 4; ++r) oacc[ct][r] *= alpha[r];

    // P -> per-wave LDS slice (swizzled) for A-frag reads (own-wave only)
#pragma unroll
    for (int nt = 0; nt < 4; ++nt) {
#pragma unroll
      for (int r = 0; r < 4; ++r) {
        int prow = lkb * 4 + r, key = nt * 16 + lm;
        *reinterpret_cast<_Float16*>(Plds + ((prow * 128 + key * 2) ^ ((prow & 7) << 4))) =
            (_Float16)p[nt][r];
      }
    }

    // O += P @ V
#pragma unroll
    for (int ks2 = 0; ks2 < 2; ++ks2) {
      half8 pf = *reinterpret_cast<const half8*>(
          Plds + ((lm * 128 + ks2 * 64 + lkb * 16) ^ ((lm & 7) << 4)));
#pragma unroll
      for (int ct = 0; ct < 16; ++ct) {
        int vrow = ct * 16 + lm;
        half8 vf = *reinterpret_cast<const half8*>(
            lds + 32768 + ((vrow * 128 + ks2 * 64 + lkb * 16) ^ ((vrow & 7) << 4)));
        oacc[ct] = __builtin_amdgcn_mfma_f32_16x16x32_f16(pf, vf, oacc[ct], 0, 0, 0);
      }
    }
    __syncthreads();  // all P/V reads done before next stage overwrites
  }

  float inv[4];
#pragma unroll
  for (int r = 0; r < 4; ++r) inv[r] = 1.0f / lrun[r];
#pragma unroll
  for (int ct = 0; ct < 16; ++ct) {
#pragma unroll
    for (int r = 0; r < 4; ++r) {
      Ob[(size_t)(q0 + lkb * 4 + r) * 256 + ct * 16 + lm] = (_Float16)(oacc[ct][r] * inv[r]);
    }
  }
}

// ---------------- launcher ----------------
// Workspace layout (MB offsets), 65 MB peak:
//   Wbf  @0    (0.5MB)
//   Xt   @1..17   -> reused as Vtb after V gemm
//   Qb   @17..33  -> reused as L (O-transpose) after attn
//   Ktb  @33..49
//   Vc   @49..65  -> reused as Ob after V-transpose
extern "C" void kernel_launch(void* const* d_in, const int* in_sizes, int n_in,
                              void* d_out, int out_size, void* d_ws, size_t ws_size,
                              hipStream_t stream) {
  (void)in_sizes; (void)n_in; (void)out_size; (void)ws_size;
  const float* X  = (const float*)d_in[0];
  const float* Wq = (const float*)d_in[1];
  const float* Wk = (const float*)d_in[2];
  const float* Wv = (const float*)d_in[3];
  const float* Wp = (const float*)d_in[4];

  char* ws = (char*)d_ws;
  _Float16* Wbf = (_Float16*)ws;                    // 4 x 65536 f16
  _Float16* Xt  = (_Float16*)(ws + (1ull  << 20));  // (B,HW,C) f16
  _Float16* Qb  = (_Float16*)(ws + (17ull << 20));  // flat (C,HW) == view (HW,C)
  _Float16* Ktb = (_Float16*)(ws + (33ull << 20));  // (HW,C) = Kc^T
  _Float16* Vc  = (_Float16*)(ws + (49ull << 20));  // temp V flat (C,HW)
  _Float16* Vtb = Xt;                               // (C,HW) view-transpose of V
  _Float16* Ob  = Vc;                               // attn out flat (HW,C)
  _Float16* Lb  = Qb;                               // O-chw-view transposed (HW,C)

  // W -> f16
  k_convert_w<<<256, 256, 0, stream>>>(Wq, Wk, Wv, Wp, Wbf);
  // X (B,256,4096) fp32 -> Xt (B,4096,256) f16
  k_transpose_f32<<<dim3(64, 4, 8), 256, 0, stream>>>(X, Xt, 256, 4096);
  // Q = Wq @ X, scaled 1/sqrt(256), flat (256,4096) f16
  k_gemm<false><<<dim3(64, 4, 8), 256, 0, stream>>>(Wbf, Xt, Qb, 256, 4096, 0, HWC, HWC, 0.0625f);
  // Kt[l][c] = (Wk @ X)^T, produced directly via role swap
  k_gemm<false><<<dim3(4, 64, 8), 256, 0, stream>>>(Xt, Wbf + 65536, Ktb, 4096, 256, HWC, 0, HWC, 1.0f);
  // Vc = Wv @ X flat (256,4096)
  k_gemm<false><<<dim3(64, 4, 8), 256, 0, stream>>>(Wbf + 131072, Xt, Vc, 256, 4096, 0, HWC, HWC, 1.0f);
  // Vt = transpose of V-view (4096,256) -> (256,4096)   [writes over Xt: dead]
  k_transpose_h16<<<dim3(4, 64, 8), 256, 0, stream>>>(Vc, Vtb, 4096, 256);
  // flash attention -> O flat (4096,256)                [writes over Vc: dead]
  k_attn<<<512, 256, 65536, stream>>>(Qb, Ktb, Vtb, Ob);
  // L = transpose of O-chw-view (256,4096) -> (4096,256) [writes over Qb: dead]
  k_transpose_h16<<<dim3(64, 4, 8), 256, 0, stream>>>(Ob, Lb, 256, 4096);
  // out = Wp @ O_chw, fp32
  k_gemm<true><<<dim3(64, 4, 8), 256, 0, stream>>>(Wbf + 196608, Lb, d_out, 256, 4096, 0, HWC, HWC, 1.0f);
}